// Round 14
// baseline (97.431 us; speedup 1.0000x reference)
//
#include <hip/hip_runtime.h>

// Nearest-prototype argmin: N=500k, K=256, D=64, fp32.
// R14 = R13 with ONE change: NBLK 1024 -> 2560. R13's counters showed the
// main kernel grid-limited at 2 waves/SIMD (Occupancy 19%, VALUBusy 41%,
// ~60% of SIMD time uncovered stall); VGPR=88 permits 4 waves/SIMD. 2560
// blocks = 10/CU issued (8 resident at the VGPR cap, 2 queued for tail
// imbalance). Main numerics (wave-autonomous fp16 MFMA, musq-augmented
// K-tile, packed argmax), LDS-staged fixup, margin net: unchanged,
// absmax=0 heritage.

#define DIM 64
#define NPROTO 256
#define NBLK 2560
#define GSZ 16              // points per iteration
#define MARGIN_ACC 0.017f   // R11's 0.015 + 0.002 pack-quantization

using f32x4 = __attribute__((ext_vector_type(4))) float;
using f16x8 = __attribute__((ext_vector_type(8))) _Float16;

__device__ __forceinline__ f16x8 cvt8(float4 a, float4 b) {
    f16x8 r;
    r[0] = (_Float16)a.x; r[1] = (_Float16)a.y;
    r[2] = (_Float16)a.z; r[3] = (_Float16)a.w;
    r[4] = (_Float16)b.x; r[5] = (_Float16)b.y;
    r[6] = (_Float16)b.z; r[7] = (_Float16)b.w;
    return r;
}

__attribute__((amdgpu_waves_per_eu(2, 4)))
__global__ void __launch_bounds__(128)
argmin_mfma_kernel(const float* __restrict__ X,
                   const float* __restrict__ mus,
                   int* __restrict__ out,
                   unsigned* __restrict__ ws_count,
                   int* __restrict__ ws_list,
                   int use_list, int n) {
    __shared__ uint2 s_pair[2][GSZ];   // 256 B total LDS

    const int tid = threadIdx.x;   // block = 128 = 2 waves
    const int w = tid >> 6;        // wave 0: protos 0-127, wave 1: 128-255
    const int l = tid & 63;
    const int lp = l & 15;         // A-row / B-col lane index
    const int lg = l >> 4;         // k-group

    // ---- A-frags: 128 protos x K64 fp16 (R11-proven layout) + musq tile --
    f16x8 ah[8][2];
    f16x8 am[8];
#pragma unroll
    for (int p = 0; p < 8; ++p) {
        const float* src = mus + (size_t)(w * 128 + p * 16 + lp) * DIM + lg * 8;
        float s = 0.f;
#pragma unroll
        for (int kt = 0; kt < 2; ++kt) {
            const float4 a = *(const float4*)(src + kt * 32);
            const float4 b = *(const float4*)(src + kt * 32 + 4);
            ah[p][kt] = cvt8(a, b);
            s = fmaf(a.x, a.x, fmaf(a.y, a.y, fmaf(a.z, a.z, fmaf(a.w, a.w, s))));
            s = fmaf(b.x, b.x, fmaf(b.y, b.y, fmaf(b.z, b.z, fmaf(b.w, b.w, s))));
        }
        // combine the 4 lg-group partial sums (same proto row lp)
        s += __shfl_xor(s, 16);
        s += __shfl_xor(s, 32);
        const float aug = -0.5f * s;
        const _Float16 hi = (_Float16)aug;
        const _Float16 lo = (_Float16)(aug - (float)hi);
        f16x8 v;
#pragma unroll
        for (int e = 0; e < 8; ++e) v[e] = (_Float16)0.f;
        if (lg == 0) { v[0] = hi; v[1] = lo; }
        am[p] = v;
    }
    f16x8 bones;
#pragma unroll
    for (int e = 0; e < 8; ++e) bones[e] = (_Float16)0.f;
    if (lg == 0) { bones[0] = (_Float16)1.f; bones[1] = (_Float16)1.f; }
    const f32x4 zero4 = {0.f, 0.f, 0.f, 0.f};

    // ---- group range ----
    const int ngroups = (n + GSZ - 1) / GSZ;   // 31250
    const int q = ngroups / NBLK, rr = ngroups % NBLK;
    const int bid = blockIdx.x;
    const int g0 = bid * q + (bid < rr ? bid : rr);
    const int cnt = q + (bid < rr ? 1 : 0);

    // ov base: kk = w*128 + p*16 + lg*4 + r  ->  ov = 255-kk (fits 8 bits)
    const int kofs = 255 - w * 128 - lg * 4;

    // prefetch group g0's B-source (lane: row g*16+lp, dims lg*8 + kt*32)
    float4 xr0, xr1, xr2, xr3;
    {
        int row = g0 * GSZ + lp; row = (row < n) ? row : (n - 1);
        const float* rp = X + (size_t)row * DIM + lg * 8;
        xr0 = *(const float4*)(rp);
        xr1 = *(const float4*)(rp + 4);
        xr2 = *(const float4*)(rp + 32);
        xr3 = *(const float4*)(rp + 36);
    }

    for (int it = 0; it < cnt; ++it) {
        const int g = g0 + it;
        const int par = it & 1;
        const bool more = (it + 1 < cnt);

        const f16x8 bx0 = cvt8(xr0, xr1);
        const f16x8 bx1 = cvt8(xr2, xr3);

        // issue next group's loads; consumed next iter -> full-iter distance
        if (more) {
            int row = (g + 1) * GSZ + lp; row = (row < n) ? row : (n - 1);
            const float* rp = X + (size_t)row * DIM + lg * 8;
            xr0 = *(const float4*)(rp);
            xr1 = *(const float4*)(rp + 4);
            xr2 = *(const float4*)(rp + 32);
            xr3 = *(const float4*)(rp + 36);
        }

        float b1 = -3.4e38f, b2 = -3.4e38f;
#pragma unroll
        for (int p = 0; p < 8; ++p) {
            // acc = (dot - musq/2) for 4 proto-slots of point col lp
            f32x4 acc = __builtin_amdgcn_mfma_f32_16x16x32_f16(
                am[p], bones, zero4, 0, 0, 0);
            acc = __builtin_amdgcn_mfma_f32_16x16x32_f16(ah[p][0], bx0, acc,
                                                         0, 0, 0);
            acc = __builtin_amdgcn_mfma_f32_16x16x32_f16(ah[p][1], bx1, acc,
                                                         0, 0, 0);
            // pack index into low 8 mantissa bits (no carry: bits cleared)
            float pv[4];
#pragma unroll
            for (int r = 0; r < 4; ++r) {
                unsigned u = __float_as_uint(acc[r]);
                u = (u & 0xFFFFFF00u) + (unsigned)(kofs - p * 16 - r);
                pv[r] = __uint_as_float(u);
            }
            const float t1a = fmaxf(pv[0], pv[1]), t2a = fminf(pv[0], pv[1]);
            const float t1b = fmaxf(pv[2], pv[3]), t2b = fminf(pv[2], pv[3]);
            const float p1 = fmaxf(t1a, t1b);
            const float p2 = fmaxf(fminf(t1a, t1b), fmaxf(t2a, t2b));
            const float nb2 = fmaxf(fminf(b1, p1), fmaxf(b2, p2));
            b1 = fmaxf(b1, p1);
            b2 = nb2;
        }
        // cross-lane over lg (lanes with same lp share a point)
#pragma unroll
        for (int m = 16; m <= 32; m <<= 1) {
            const float o1 = __shfl_xor(b1, m);
            const float o2 = __shfl_xor(b2, m);
            const float nb2 = fmaxf(fminf(b1, o1), fmaxf(b2, o2));
            b1 = fmaxf(b1, o1);
            b2 = nb2;
        }
        if (w == 1 && l < GSZ)
            s_pair[par][l] = make_uint2(__float_as_uint(b1),
                                        __float_as_uint(b2));
        __syncthreads();

        bool fl = false;
        const int i = g * GSZ + l;   // valid only for l < GSZ
        if (w == 0 && l < GSZ) {
            const uint2 o = s_pair[par][l];
            const float o1 = __uint_as_float(o.x), o2 = __uint_as_float(o.y);
            const float nb2 = fmaxf(fminf(b1, o1), fmaxf(b2, o2));
            b1 = fmaxf(b1, o1);
            b2 = nb2;
            const unsigned u1 = __float_as_uint(b1);
            const int k1 = 255 - (int)(u1 & 0xFFu);
            const float f1 = __uint_as_float(u1 & 0xFFFFFF00u);
            const float f2 =
                __uint_as_float(__float_as_uint(b2) & 0xFFFFFF00u);
            const bool close = (f1 - f2) < MARGIN_ACC;
            if (i < n) {
                if (use_list) {
                    out[i] = k1;
                    fl = close;
                } else {
                    out[i] = (int)((unsigned)k1 | (close ? 0x80000000u : 0u));
                }
            }
        }
        if (use_list) {
            const unsigned long long mask = __ballot(fl);  // wave1: 0
            if (mask) {
                unsigned base = 0;
                if (l == 0)
                    base = atomicAdd(ws_count, (unsigned)__popcll(mask));
                base = __shfl(base, 0);
                if (fl)
                    ws_list[base + __popcll(mask & ((1ull << l) - 1))] = i;
            }
        }
    }
}

#define MSTRIDE 65   // padded row stride: bank (l+d)%32, 2 lanes/bank = free

// LDS-staged exact-fp32 fixup: stage all mus (+msq, R2 4-stripe order) into
// LDS once per block; one point per wave (R11-proven register shape).
__global__ void __launch_bounds__(256)
fixup_lds_kernel(const float* __restrict__ X, const float* __restrict__ mus,
                 const unsigned* __restrict__ ws_count,
                 const int* __restrict__ ws_list, int* __restrict__ out) {
    __shared__ float s_mu[NPROTO * MSTRIDE];  // 65 KB
    __shared__ float s_msq[NPROTO];

    const int tid = threadIdx.x;
    // stage: thread t -> proto t (msq in the exact recompute order)
    {
        const float4* mr = (const float4*)(mus + (size_t)tid * DIM);
        float q0 = 0.f, q1 = 0.f, q2 = 0.f, q3 = 0.f;
#pragma unroll
        for (int qq = 0; qq < 16; ++qq) {
            const float4 mv = mr[qq];
            const int base = tid * MSTRIDE + qq * 4;
            s_mu[base]     = mv.x;
            s_mu[base + 1] = mv.y;
            s_mu[base + 2] = mv.z;
            s_mu[base + 3] = mv.w;
            q0 = fmaf(mv.x, mv.x, q0);
            q1 = fmaf(mv.y, mv.y, q1);
            q2 = fmaf(mv.z, mv.z, q2);
            q3 = fmaf(mv.w, mv.w, q3);
        }
        s_msq[tid] = (q0 + q1) + (q2 + q3);
    }
    __syncthreads();

    const int l = tid & 63;
    const int gw = (int)((blockIdx.x * blockDim.x + tid) >> 6);
    const int NW = (int)((gridDim.x * blockDim.x) >> 6);
    const int nf = (int)*ws_count;

    for (int j = gw; j < nf; j += NW) {
        const int pt = ws_list[j];
        const float4* xr = (const float4*)(X + (size_t)pt * DIM);
        float4 xv[16];
        float a0 = 0.f, a1 = 0.f, a2 = 0.f, a3 = 0.f;
#pragma unroll
        for (int qq = 0; qq < 16; ++qq) {
            xv[qq] = xr[qq];
            a0 = fmaf(xv[qq].x, xv[qq].x, a0);
            a1 = fmaf(xv[qq].y, xv[qq].y, a1);
            a2 = fmaf(xv[qq].z, xv[qq].z, a2);
            a3 = fmaf(xv[qq].w, xv[qq].w, a3);
        }
        const float xsq = (a0 + a1) + (a2 + a3);
        float b1 = 3.4e38f;
        int k1 = 0;
#pragma unroll
        for (int e = 0; e < 4; ++e) {
            const int p = e * 64 + l;           // k ascending per lane
            const float* mr = &s_mu[p * MSTRIDE];
            float d0 = 0.f, d1 = 0.f, d2 = 0.f, d3 = 0.f;
#pragma unroll
            for (int qq = 0; qq < 16; ++qq) {
                d0 = fmaf(mr[qq * 4],     xv[qq].x, d0);
                d1 = fmaf(mr[qq * 4 + 1], xv[qq].y, d1);
                d2 = fmaf(mr[qq * 4 + 2], xv[qq].z, d2);
                d3 = fmaf(mr[qq * 4 + 3], xv[qq].w, d3);
            }
            const float dot = (d0 + d1) + (d2 + d3);
            const float dd = (xsq - 2.0f * dot) + s_msq[p];
            if (dd < b1) { b1 = dd; k1 = p; }   // strict <: first-min
        }
#pragma unroll
        for (int mm = 1; mm < 64; mm <<= 1) {
            const float ob = __shfl_xor(b1, mm);
            const int ok = __shfl_xor(k1, mm);
            if (ob < b1 || (ob == b1 && ok < k1)) { b1 = ob; k1 = ok; }
        }
        if (l == 0) out[pt] = k1;
    }
}

// Exact-fp32 wave-cooperative recompute of one point (R2-proven order) —
// used by the fallback scan path only.
__device__ __forceinline__ int recompute_point(const float* __restrict__ X,
                                               const float* __restrict__ mus,
                                               int pt, int l) {
    const float4* xr = (const float4*)(X + (size_t)pt * DIM);
    float4 xv[16];
    float xa0 = 0.f, xa1 = 0.f, xa2 = 0.f, xa3 = 0.f;
#pragma unroll
    for (int qq = 0; qq < 16; ++qq) {
        xv[qq] = xr[qq];
        xa0 = fmaf(xv[qq].x, xv[qq].x, xa0);
        xa1 = fmaf(xv[qq].y, xv[qq].y, xa1);
        xa2 = fmaf(xv[qq].z, xv[qq].z, xa2);
        xa3 = fmaf(xv[qq].w, xv[qq].w, xa3);
    }
    const float xsq = (xa0 + xa1) + (xa2 + xa3);
    float b1 = 3.4e38f; int k1 = 0;
#pragma unroll
    for (int e = 0; e < 4; ++e) {
        const int p = l * 4 + e;
        const float4* mr = (const float4*)(mus + (size_t)p * DIM);
        float d0 = 0.f, d1 = 0.f, d2a = 0.f, d3 = 0.f;
        float q0 = 0.f, q1 = 0.f, q2 = 0.f, q3 = 0.f;
#pragma unroll
        for (int qq = 0; qq < 16; ++qq) {
            const float4 mv = mr[qq];
            d0 = fmaf(mv.x, xv[qq].x, d0);
            d1 = fmaf(mv.y, xv[qq].y, d1);
            d2a = fmaf(mv.z, xv[qq].z, d2a);
            d3 = fmaf(mv.w, xv[qq].w, d3);
            q0 = fmaf(mv.x, mv.x, q0);
            q1 = fmaf(mv.y, mv.y, q1);
            q2 = fmaf(mv.z, mv.z, q2);
            q3 = fmaf(mv.w, mv.w, q3);
        }
        const float dot = (d0 + d1) + (d2a + d3);
        const float msq = (q0 + q1) + (q2 + q3);
        const float dd = (xsq - 2.0f * dot) + msq;
        if (dd < b1) { b1 = dd; k1 = p; }
    }
#pragma unroll
    for (int mm = 1; mm < 64; mm <<= 1) {
        const float ob = __shfl_xor(b1, mm);
        const int ok = __shfl_xor(k1, mm);
        if (ob < b1 || (ob == b1 && ok < k1)) { b1 = ob; k1 = ok; }
    }
    return k1;
}

// Fallback scan fixup (flag bit 31 in out), used if ws too small.
__global__ void __launch_bounds__(256)
fixup_scan_kernel(const float* __restrict__ X, const float* __restrict__ mus,
                  int* __restrict__ out, int n) {
    const int gw = (int)((blockIdx.x * blockDim.x + threadIdx.x) >> 6);
    const int l = threadIdx.x & 63;
    const int NW = (int)((gridDim.x * blockDim.x) >> 6);
    const int chunk = (n + NW - 1) / NW;
    const int base = gw * chunk;
    const int end = (base + chunk < n) ? (base + chunk) : n;
    for (int s = base; s < end; s += 64) {
        const int i = s + l;
        const int v = (i < end) ? out[i] : 0;
        const bool flg = (i < end) && ((unsigned)v & 0x80000000u);
        unsigned long long m = __ballot(flg);
        while (m) {
            const int src = (int)__ffsll((unsigned long long)m) - 1;
            m &= m - 1;
            const int pt = __shfl(i, src);
            const int k1 = recompute_point(X, mus, pt, l);
            if (l == 0) out[pt] = k1;
        }
    }
}

extern "C" void kernel_launch(void* const* d_in, const int* in_sizes, int n_in,
                              void* d_out, int out_size, void* d_ws, size_t ws_size,
                              hipStream_t stream) {
    const float* X = (const float*)d_in[0];
    const float* mus = (const float*)d_in[1];
    int* out = (int*)d_out;
    const int n = in_sizes[0] / DIM;  // 500000

    unsigned* ws_count = (unsigned*)d_ws;
    int* ws_list = (int*)((char*)d_ws + 16);
    const int use_list = (ws_size >= 16 + (size_t)n * 4) ? 1 : 0;

    if (use_list) {
        hipMemsetAsync(d_ws, 0, 16, stream);  // reset append counter
    }

    argmin_mfma_kernel<<<NBLK, 128, 0, stream>>>(X, mus, out, ws_count,
                                                 ws_list, use_list, n);
    if (use_list) {
        fixup_lds_kernel<<<512, 256, 0, stream>>>(X, mus, ws_count, ws_list,
                                                  out);
    } else {
        fixup_scan_kernel<<<512, 256, 0, stream>>>(X, mus, out, n);
    }
}

// Round 15
// 83.290 us; speedup vs baseline: 1.1698x; 1.1698x over previous
//
#include <hip/hip_runtime.h>

// Nearest-prototype argmin: N=500k, K=256, D=64, fp32.
// R15 = R13 (NBLK=1024) with ONE structural fix: __syncthreads() emitted
// `s_waitcnt vmcnt(0)` before s_barrier (m97's documented drain), killing
// the cross-iteration X prefetch every 16-point iteration (~2300 stall
// cyc/iter measured). Replaced with the HK-template barrier:
//   s_waitcnt lgkmcnt(0)  (orders wave1's ds_write of s_pair)
//   __builtin_amdgcn_s_barrier()  (does NOT drain vmcnt -> prefetch flies)
//   sched_barrier(0)  (rule #18: stop hoisting across the asm wait)
// Everything else (wave-autonomous fp16 MFMA main, packed argmax, margin
// 0.017 + LDS-staged exact-fp32 fixup) byte-identical to R13 (absmax=0).

#define DIM 64
#define NPROTO 256
#define NBLK 1024
#define GSZ 16              // points per iteration
#define MARGIN_ACC 0.017f   // R11's 0.015 + 0.002 pack-quantization

using f32x4 = __attribute__((ext_vector_type(4))) float;
using f16x8 = __attribute__((ext_vector_type(8))) _Float16;

__device__ __forceinline__ f16x8 cvt8(float4 a, float4 b) {
    f16x8 r;
    r[0] = (_Float16)a.x; r[1] = (_Float16)a.y;
    r[2] = (_Float16)a.z; r[3] = (_Float16)a.w;
    r[4] = (_Float16)b.x; r[5] = (_Float16)b.y;
    r[6] = (_Float16)b.z; r[7] = (_Float16)b.w;
    return r;
}

// barrier that does NOT drain vmcnt: in-flight global prefetch loads
// survive; only LDS ordering is enforced.
__device__ __forceinline__ void barrier_keep_vmcnt() {
    asm volatile("s_waitcnt lgkmcnt(0)" ::: "memory");
    __builtin_amdgcn_s_barrier();
    __builtin_amdgcn_sched_barrier(0);
}

__attribute__((amdgpu_waves_per_eu(2, 4)))
__global__ void __launch_bounds__(128)
argmin_mfma_kernel(const float* __restrict__ X,
                   const float* __restrict__ mus,
                   int* __restrict__ out,
                   unsigned* __restrict__ ws_count,
                   int* __restrict__ ws_list,
                   int use_list, int n) {
    __shared__ uint2 s_pair[2][GSZ];   // 256 B total LDS

    const int tid = threadIdx.x;   // block = 128 = 2 waves
    const int w = tid >> 6;        // wave 0: protos 0-127, wave 1: 128-255
    const int l = tid & 63;
    const int lp = l & 15;         // A-row / B-col lane index
    const int lg = l >> 4;         // k-group

    // ---- A-frags: 128 protos x K64 fp16 (R11-proven layout) + musq tile --
    f16x8 ah[8][2];
    f16x8 am[8];
#pragma unroll
    for (int p = 0; p < 8; ++p) {
        const float* src = mus + (size_t)(w * 128 + p * 16 + lp) * DIM + lg * 8;
        float s = 0.f;
#pragma unroll
        for (int kt = 0; kt < 2; ++kt) {
            const float4 a = *(const float4*)(src + kt * 32);
            const float4 b = *(const float4*)(src + kt * 32 + 4);
            ah[p][kt] = cvt8(a, b);
            s = fmaf(a.x, a.x, fmaf(a.y, a.y, fmaf(a.z, a.z, fmaf(a.w, a.w, s))));
            s = fmaf(b.x, b.x, fmaf(b.y, b.y, fmaf(b.z, b.z, fmaf(b.w, b.w, s))));
        }
        // combine the 4 lg-group partial sums (same proto row lp)
        s += __shfl_xor(s, 16);
        s += __shfl_xor(s, 32);
        const float aug = -0.5f * s;
        const _Float16 hi = (_Float16)aug;
        const _Float16 lo = (_Float16)(aug - (float)hi);
        f16x8 v;
#pragma unroll
        for (int e = 0; e < 8; ++e) v[e] = (_Float16)0.f;
        if (lg == 0) { v[0] = hi; v[1] = lo; }
        am[p] = v;
    }
    f16x8 bones;
#pragma unroll
    for (int e = 0; e < 8; ++e) bones[e] = (_Float16)0.f;
    if (lg == 0) { bones[0] = (_Float16)1.f; bones[1] = (_Float16)1.f; }
    const f32x4 zero4 = {0.f, 0.f, 0.f, 0.f};

    // ---- group range ----
    const int ngroups = (n + GSZ - 1) / GSZ;   // 31250
    const int q = ngroups / NBLK, rr = ngroups % NBLK;
    const int bid = blockIdx.x;
    const int g0 = bid * q + (bid < rr ? bid : rr);
    const int cnt = q + (bid < rr ? 1 : 0);

    // ov base: kk = w*128 + p*16 + lg*4 + r  ->  ov = 255-kk (fits 8 bits)
    const int kofs = 255 - w * 128 - lg * 4;

    // prefetch group g0's B-source (lane: row g*16+lp, dims lg*8 + kt*32)
    float4 xr0, xr1, xr2, xr3;
    {
        int row = g0 * GSZ + lp; row = (row < n) ? row : (n - 1);
        const float* rp = X + (size_t)row * DIM + lg * 8;
        xr0 = *(const float4*)(rp);
        xr1 = *(const float4*)(rp + 4);
        xr2 = *(const float4*)(rp + 32);
        xr3 = *(const float4*)(rp + 36);
    }

    for (int it = 0; it < cnt; ++it) {
        const int g = g0 + it;
        const int par = it & 1;
        const bool more = (it + 1 < cnt);

        const f16x8 bx0 = cvt8(xr0, xr1);
        const f16x8 bx1 = cvt8(xr2, xr3);

        // issue next group's loads; consumed next iter -> full-iter distance
        // (loads now survive the barrier: no vmcnt drain)
        if (more) {
            int row = (g + 1) * GSZ + lp; row = (row < n) ? row : (n - 1);
            const float* rp = X + (size_t)row * DIM + lg * 8;
            xr0 = *(const float4*)(rp);
            xr1 = *(const float4*)(rp + 4);
            xr2 = *(const float4*)(rp + 32);
            xr3 = *(const float4*)(rp + 36);
        }

        float b1 = -3.4e38f, b2 = -3.4e38f;
#pragma unroll
        for (int p = 0; p < 8; ++p) {
            // acc = (dot - musq/2) for 4 proto-slots of point col lp
            f32x4 acc = __builtin_amdgcn_mfma_f32_16x16x32_f16(
                am[p], bones, zero4, 0, 0, 0);
            acc = __builtin_amdgcn_mfma_f32_16x16x32_f16(ah[p][0], bx0, acc,
                                                         0, 0, 0);
            acc = __builtin_amdgcn_mfma_f32_16x16x32_f16(ah[p][1], bx1, acc,
                                                         0, 0, 0);
            // pack index into low 8 mantissa bits (no carry: bits cleared)
            float pv[4];
#pragma unroll
            for (int r = 0; r < 4; ++r) {
                unsigned u = __float_as_uint(acc[r]);
                u = (u & 0xFFFFFF00u) + (unsigned)(kofs - p * 16 - r);
                pv[r] = __uint_as_float(u);
            }
            const float t1a = fmaxf(pv[0], pv[1]), t2a = fminf(pv[0], pv[1]);
            const float t1b = fmaxf(pv[2], pv[3]), t2b = fminf(pv[2], pv[3]);
            const float p1 = fmaxf(t1a, t1b);
            const float p2 = fmaxf(fminf(t1a, t1b), fmaxf(t2a, t2b));
            const float nb2 = fmaxf(fminf(b1, p1), fmaxf(b2, p2));
            b1 = fmaxf(b1, p1);
            b2 = nb2;
        }
        // cross-lane over lg (lanes with same lp share a point)
#pragma unroll
        for (int m = 16; m <= 32; m <<= 1) {
            const float o1 = __shfl_xor(b1, m);
            const float o2 = __shfl_xor(b2, m);
            const float nb2 = fmaxf(fminf(b1, o1), fmaxf(b2, o2));
            b1 = fmaxf(b1, o1);
            b2 = nb2;
        }
        if (w == 1 && l < GSZ)
            s_pair[par][l] = make_uint2(__float_as_uint(b1),
                                        __float_as_uint(b2));
        barrier_keep_vmcnt();

        bool fl = false;
        const int i = g * GSZ + l;   // valid only for l < GSZ
        if (w == 0 && l < GSZ) {
            const uint2 o = s_pair[par][l];
            const float o1 = __uint_as_float(o.x), o2 = __uint_as_float(o.y);
            const float nb2 = fmaxf(fminf(b1, o1), fmaxf(b2, o2));
            b1 = fmaxf(b1, o1);
            b2 = nb2;
            const unsigned u1 = __float_as_uint(b1);
            const int k1 = 255 - (int)(u1 & 0xFFu);
            const float f1 = __uint_as_float(u1 & 0xFFFFFF00u);
            const float f2 =
                __uint_as_float(__float_as_uint(b2) & 0xFFFFFF00u);
            const bool close = (f1 - f2) < MARGIN_ACC;
            if (i < n) {
                if (use_list) {
                    out[i] = k1;
                    fl = close;
                } else {
                    out[i] = (int)((unsigned)k1 | (close ? 0x80000000u : 0u));
                }
            }
        }
        if (use_list) {
            const unsigned long long mask = __ballot(fl);  // wave1: 0
            if (mask) {
                unsigned base = 0;
                if (l == 0)
                    base = atomicAdd(ws_count, (unsigned)__popcll(mask));
                base = __shfl(base, 0);
                if (fl)
                    ws_list[base + __popcll(mask & ((1ull << l) - 1))] = i;
            }
        }
    }
}

#define MSTRIDE 65   // padded row stride: bank (l+d)%32, 2 lanes/bank = free

// LDS-staged exact-fp32 fixup: stage all mus (+msq, R2 4-stripe order) into
// LDS once per block; one point per wave (R11-proven register shape).
__global__ void __launch_bounds__(256)
fixup_lds_kernel(const float* __restrict__ X, const float* __restrict__ mus,
                 const unsigned* __restrict__ ws_count,
                 const int* __restrict__ ws_list, int* __restrict__ out) {
    __shared__ float s_mu[NPROTO * MSTRIDE];  // 65 KB
    __shared__ float s_msq[NPROTO];

    const int tid = threadIdx.x;
    // stage: thread t -> proto t (msq in the exact recompute order)
    {
        const float4* mr = (const float4*)(mus + (size_t)tid * DIM);
        float q0 = 0.f, q1 = 0.f, q2 = 0.f, q3 = 0.f;
#pragma unroll
        for (int qq = 0; qq < 16; ++qq) {
            const float4 mv = mr[qq];
            const int base = tid * MSTRIDE + qq * 4;
            s_mu[base]     = mv.x;
            s_mu[base + 1] = mv.y;
            s_mu[base + 2] = mv.z;
            s_mu[base + 3] = mv.w;
            q0 = fmaf(mv.x, mv.x, q0);
            q1 = fmaf(mv.y, mv.y, q1);
            q2 = fmaf(mv.z, mv.z, q2);
            q3 = fmaf(mv.w, mv.w, q3);
        }
        s_msq[tid] = (q0 + q1) + (q2 + q3);
    }
    __syncthreads();

    const int l = tid & 63;
    const int gw = (int)((blockIdx.x * blockDim.x + tid) >> 6);
    const int NW = (int)((gridDim.x * blockDim.x) >> 6);
    const int nf = (int)*ws_count;

    for (int j = gw; j < nf; j += NW) {
        const int pt = ws_list[j];
        const float4* xr = (const float4*)(X + (size_t)pt * DIM);
        float4 xv[16];
        float a0 = 0.f, a1 = 0.f, a2 = 0.f, a3 = 0.f;
#pragma unroll
        for (int qq = 0; qq < 16; ++qq) {
            xv[qq] = xr[qq];
            a0 = fmaf(xv[qq].x, xv[qq].x, a0);
            a1 = fmaf(xv[qq].y, xv[qq].y, a1);
            a2 = fmaf(xv[qq].z, xv[qq].z, a2);
            a3 = fmaf(xv[qq].w, xv[qq].w, a3);
        }
        const float xsq = (a0 + a1) + (a2 + a3);
        float b1 = 3.4e38f;
        int k1 = 0;
#pragma unroll
        for (int e = 0; e < 4; ++e) {
            const int p = e * 64 + l;           // k ascending per lane
            const float* mr = &s_mu[p * MSTRIDE];
            float d0 = 0.f, d1 = 0.f, d2 = 0.f, d3 = 0.f;
#pragma unroll
            for (int qq = 0; qq < 16; ++qq) {
                d0 = fmaf(mr[qq * 4],     xv[qq].x, d0);
                d1 = fmaf(mr[qq * 4 + 1], xv[qq].y, d1);
                d2 = fmaf(mr[qq * 4 + 2], xv[qq].z, d2);
                d3 = fmaf(mr[qq * 4 + 3], xv[qq].w, d3);
            }
            const float dot = (d0 + d1) + (d2 + d3);
            const float dd = (xsq - 2.0f * dot) + s_msq[p];
            if (dd < b1) { b1 = dd; k1 = p; }   // strict <: first-min
        }
#pragma unroll
        for (int mm = 1; mm < 64; mm <<= 1) {
            const float ob = __shfl_xor(b1, mm);
            const int ok = __shfl_xor(k1, mm);
            if (ob < b1 || (ob == b1 && ok < k1)) { b1 = ob; k1 = ok; }
        }
        if (l == 0) out[pt] = k1;
    }
}

// Exact-fp32 wave-cooperative recompute of one point (R2-proven order) —
// used by the fallback scan path only.
__device__ __forceinline__ int recompute_point(const float* __restrict__ X,
                                               const float* __restrict__ mus,
                                               int pt, int l) {
    const float4* xr = (const float4*)(X + (size_t)pt * DIM);
    float4 xv[16];
    float xa0 = 0.f, xa1 = 0.f, xa2 = 0.f, xa3 = 0.f;
#pragma unroll
    for (int qq = 0; qq < 16; ++qq) {
        xv[qq] = xr[qq];
        xa0 = fmaf(xv[qq].x, xv[qq].x, xa0);
        xa1 = fmaf(xv[qq].y, xv[qq].y, xa1);
        xa2 = fmaf(xv[qq].z, xv[qq].z, xa2);
        xa3 = fmaf(xv[qq].w, xv[qq].w, xa3);
    }
    const float xsq = (xa0 + xa1) + (xa2 + xa3);
    float b1 = 3.4e38f; int k1 = 0;
#pragma unroll
    for (int e = 0; e < 4; ++e) {
        const int p = l * 4 + e;
        const float4* mr = (const float4*)(mus + (size_t)p * DIM);
        float d0 = 0.f, d1 = 0.f, d2a = 0.f, d3 = 0.f;
        float q0 = 0.f, q1 = 0.f, q2 = 0.f, q3 = 0.f;
#pragma unroll
        for (int qq = 0; qq < 16; ++qq) {
            const float4 mv = mr[qq];
            d0 = fmaf(mv.x, xv[qq].x, d0);
            d1 = fmaf(mv.y, xv[qq].y, d1);
            d2a = fmaf(mv.z, xv[qq].z, d2a);
            d3 = fmaf(mv.w, xv[qq].w, d3);
            q0 = fmaf(mv.x, mv.x, q0);
            q1 = fmaf(mv.y, mv.y, q1);
            q2 = fmaf(mv.z, mv.z, q2);
            q3 = fmaf(mv.w, mv.w, q3);
        }
        const float dot = (d0 + d1) + (d2a + d3);
        const float msq = (q0 + q1) + (q2 + q3);
        const float dd = (xsq - 2.0f * dot) + msq;
        if (dd < b1) { b1 = dd; k1 = p; }
    }
#pragma unroll
    for (int mm = 1; mm < 64; mm <<= 1) {
        const float ob = __shfl_xor(b1, mm);
        const int ok = __shfl_xor(k1, mm);
        if (ob < b1 || (ob == b1 && ok < k1)) { b1 = ob; k1 = ok; }
    }
    return k1;
}

// Fallback scan fixup (flag bit 31 in out), used if ws too small.
__global__ void __launch_bounds__(256)
fixup_scan_kernel(const float* __restrict__ X, const float* __restrict__ mus,
                  int* __restrict__ out, int n) {
    const int gw = (int)((blockIdx.x * blockDim.x + threadIdx.x) >> 6);
    const int l = threadIdx.x & 63;
    const int NW = (int)((gridDim.x * blockDim.x) >> 6);
    const int chunk = (n + NW - 1) / NW;
    const int base = gw * chunk;
    const int end = (base + chunk < n) ? (base + chunk) : n;
    for (int s = base; s < end; s += 64) {
        const int i = s + l;
        const int v = (i < end) ? out[i] : 0;
        const bool flg = (i < end) && ((unsigned)v & 0x80000000u);
        unsigned long long m = __ballot(flg);
        while (m) {
            const int src = (int)__ffsll((unsigned long long)m) - 1;
            m &= m - 1;
            const int pt = __shfl(i, src);
            const int k1 = recompute_point(X, mus, pt, l);
            if (l == 0) out[pt] = k1;
        }
    }
}

extern "C" void kernel_launch(void* const* d_in, const int* in_sizes, int n_in,
                              void* d_out, int out_size, void* d_ws, size_t ws_size,
                              hipStream_t stream) {
    const float* X = (const float*)d_in[0];
    const float* mus = (const float*)d_in[1];
    int* out = (int*)d_out;
    const int n = in_sizes[0] / DIM;  // 500000

    unsigned* ws_count = (unsigned*)d_ws;
    int* ws_list = (int*)((char*)d_ws + 16);
    const int use_list = (ws_size >= 16 + (size_t)n * 4) ? 1 : 0;

    if (use_list) {
        hipMemsetAsync(d_ws, 0, 16, stream);  // reset append counter
    }

    argmin_mfma_kernel<<<NBLK, 128, 0, stream>>>(X, mus, out, ws_count,
                                                 ws_list, use_list, n);
    if (use_list) {
        fixup_lds_kernel<<<512, 256, 0, stream>>>(X, mus, ws_count, ws_list,
                                                  out);
    } else {
        fixup_scan_kernel<<<512, 256, 0, stream>>>(X, mus, out, n);
    }
}